// Round 9
// baseline (437.357 us; speedup 1.0000x reference)
//
#include <hip/hip_runtime.h>
#include <hip/hip_bf16.h>
#include <stdint.h>

using u16 = unsigned short;
using u32 = unsigned int;
using u8  = unsigned char;

#define NB 64
#define TT 128
#define DK 768
#define MC 30

typedef float f32x16 __attribute__((ext_vector_type(16)));
typedef __bf16 bf16x8 __attribute__((ext_vector_type(8)));
typedef long long ll;
typedef __attribute__((ext_vector_type(2))) ll ll2;

__device__ inline void unpack2(u32 u, float& lo, float& hi){
  union{u32 i; float f;} a, b; a.i = u << 16; b.i = u & 0xFFFF0000u; lo = a.f; hi = b.f;
}
__device__ inline u16 f2bf(float f){
  union{u32 i; float f;} v; v.f = f;
  u32 r = v.i + 0x7FFFu + ((v.i >> 16) & 1u);
  return (u16)(r >> 16);
}
__device__ inline u32 pack2bf(float a, float b){ return (u32)f2bf(a) | ((u32)f2bf(b) << 16); }

// ---------------- fp8 e4m3fn pack/unpack helpers ----------------
#if __has_builtin(__builtin_amdgcn_cvt_pk_fp8_f32)
template<bool HIW>
__device__ inline u32 pk_fp8(float a, float b, u32 old){
  return (u32)__builtin_amdgcn_cvt_pk_fp8_f32(a, b, (int)old, HIW);
}
#else
__device__ inline u8 f2fp8_1(float f){
  union{float f; u32 u;} v; v.f = f;
  u32 s = (v.u >> 24) & 0x80u;
  u32 abs = v.u & 0x7fffffffu;
  if (abs < 0x3c800000u){
    float sc = fabsf(f) * 512.0f;
    int m = (int)rintf(sc);
    return (u8)(s | (u32)m);
  }
  u32 e8 = abs >> 23; u32 mant = abs & 0x7fffffu;
  u32 m3 = mant >> 20; u32 rest = mant & 0xfffffu;
  u32 rb = (rest > 0x80000u) || (rest == 0x80000u && (m3 & 1u));
  m3 += rb;
  u32 E = e8 - 120u;
  if (m3 == 8u){ m3 = 0u; E += 1u; }
  if (E >= 16u || (E == 15u && m3 == 7u)) return (u8)(s | 0x7Eu);
  return (u8)(s | (E << 3) | m3);
}
template<bool HIW>
__device__ inline u32 pk_fp8(float a, float b, u32 old){
  u32 w = (u32)f2fp8_1(a) | ((u32)f2fp8_1(b) << 8);
  return HIW ? ((old & 0x0000FFFFu) | (w << 16)) : ((old & 0xFFFF0000u) | w);
}
#endif

#if __has_builtin(__builtin_amdgcn_cvt_pk_f32_fp8)
__device__ inline void upk_fp8x4(u32 w, float* x){
  auto a0 = __builtin_amdgcn_cvt_pk_f32_fp8((int)w, false);
  auto a1 = __builtin_amdgcn_cvt_pk_f32_fp8((int)w, true);
  x[0] = a0[0]; x[1] = a0[1]; x[2] = a1[0]; x[3] = a1[1];
}
#else
__device__ inline float fp8_1(u32 byte){
  u32 s = (byte & 0x80u) << 24;
  u32 E = (byte >> 3) & 15u, M = byte & 7u;
  union{u32 u; float f;} v;
  if (E == 0){ v.f = (float)M * (1.0f/512.0f); v.u |= s; }
  else v.u = s | ((E + 120u) << 23) | (M << 20);
  return v.f;
}
__device__ inline void upk_fp8x4(u32 w, float* x){
  x[0] = fp8_1(w & 255u); x[1] = fp8_1((w >> 8) & 255u);
  x[2] = fp8_1((w >> 16) & 255u); x[3] = fp8_1(w >> 24);
}
#endif

// ---------------- weight prep ----------------
// w2p: fp8 [tap][oc32][ic32] linear, 1024 B per tap (A-frags read straight from global)
// w1c: bf16 MFMA A-frag table [dy][oc32][k16], k = dx*2 + c (dx>=5 zero), swizzled
__global__ __launch_bounds__(256) void prep_w_k(const float* __restrict__ w2,
    const float* __restrict__ w1, u8* __restrict__ w2p, u16* __restrict__ w1c){
  int bidx = blockIdx.x;
  if (bidx < 25){
    int tap = bidx;
    int i = threadIdx.x;
    int oc = i >> 3, q = i & 7, ic0 = q * 4;
    float v[4];
    #pragma unroll
    for (int j = 0; j < 4; ++j)
      v[j] = (oc < MC && ic0 + j < MC) ? w2[(oc*MC + ic0 + j)*25 + tap] : 0.f;
    u32 w = pk_fp8<false>(v[0], v[1], 0u);
    w = pk_fp8<true>(v[2], v[3], w);
    *(u32*)(w2p + tap*1024 + oc*32 + q*4) = w;
  } else {
    for (int i = threadIdx.x; i < 2560; i += 256){
      int dy = i >> 9; int rem = i & 511; int oc = rem >> 4; int k = rem & 15;
      int dx = k >> 1, c = k & 1;
      float v = (oc < MC && dx < 5) ? w1[(oc*2 + c)*25 + dy*5 + dx] : 0.f;
      int byteoff = dy*1024 + (((oc<<5) + (k<<1)) ^ ((oc&7)<<4));
      *(u16*)((char*)w1c + byteoff) = f2bf(v);
    }
  }
}

// ---------------- kernel 1: row norms + bf16 conversion ----------------
__global__ __launch_bounds__(256) void row_norms_k(const float* __restrict__ q, const float* __restrict__ k,
    float* __restrict__ qq, float* __restrict__ kk,
    u16* __restrict__ qb16, u16* __restrict__ kb16){
  int wave = blockIdx.x * 4 + (threadIdx.x >> 6);
  int lane = threadIdx.x & 63;
  const float* src; float* dst; u16* bdst; int row;
  if (wave < NB * TT) { src = q; dst = qq; bdst = qb16; row = wave; }
  else                { src = k; dst = kk; bdst = kb16; row = wave - NB * TT; }
  const float4* p = (const float4*)(src + (size_t)row * DK + lane * 12);
  u16* ob = bdst + (size_t)row * DK + lane * 12;
  float s = 0.f;
  #pragma unroll
  for (int t = 0; t < 3; ++t){
    float4 v = p[t];
    s += v.x*v.x + v.y*v.y + v.z*v.z + v.w*v.w;
    uint2 st; st.x = pack2bf(v.x, v.y); st.y = pack2bf(v.z, v.w);
    *(uint2*)(ob + t*4) = st;
  }
  #pragma unroll
  for (int o = 32; o; o >>= 1) s += __shfl_xor(s, o);
  if (lane == 0) dst[row] = s;
}

// ---------------- kernel 2: cdist via bf16 MFMA + P + mask ----------------
// inb output: u32 per (b,y,x): lo = bf16(D), hi = bf16(P)
__global__ __launch_bounds__(256) void cdist_mfma_k(
    const u16* __restrict__ Qb16, const u16* __restrict__ Kb16,
    const float* __restrict__ qq, const float* __restrict__ kk,
    const int* __restrict__ qlen, const int* __restrict__ klen,
    const float* __restrict__ qR, const float* __restrict__ kR,
    float* __restrict__ Dout, u32* __restrict__ inb){
  __shared__ __align__(16) char qs[32 * 1536];    // [32 rows][768 k] bf16, swizzled
  __shared__ __align__(16) char ksm[128 * 256];   // [128 cols][128 k] bf16, swizzled
  int rt = blockIdx.x;
  int b  = blockIdx.y;
  int r0 = rt * 32;
  int tid = threadIdx.x;
  const u16* Qg = Qb16 + ((size_t)b * TT + r0) * DK;
  const u16* Kg = Kb16 + (size_t)b * TT * DK;
  for (int idx = tid; idx < 3072; idx += 256){
    int row = idx / 96, ch = idx - row * 96;
    uint4 v = *(const uint4*)(Qg + row * DK + ch * 8);
    *(uint4*)(qs + row * 1536 + ((ch * 16) ^ ((row & 7) << 4))) = v;
  }
  int lane = tid & 63, w = tid >> 6;
  int hi = lane >> 5, l31 = lane & 31;
  int col = w * 32 + l31;
  f32x16 acc;
  #pragma unroll
  for (int r = 0; r < 16; ++r) acc[r] = 0.f;
  for (int kc = 0; kc < DK; kc += 128){
    __syncthreads();
    for (int idx = tid; idx < 2048; idx += 256){
      int c = idx >> 4, j = idx & 15;
      uint4 v = *(const uint4*)(Kg + c * DK + kc + j * 8);
      *(uint4*)(ksm + c * 256 + ((j * 16) ^ ((c & 7) << 4))) = v;
    }
    __syncthreads();
    #pragma unroll
    for (int k8 = 0; k8 < 8; ++k8){
      bf16x8 a  = *(const bf16x8*)(qs  + l31 * 1536 + (((kc + k8*16 + hi*8) * 2) ^ ((l31 & 7) << 4)));
      bf16x8 bv = *(const bf16x8*)(ksm + col * 256  + (((k8*16 + hi*8) * 2) ^ ((col & 7) << 4)));
      acc = __builtin_amdgcn_mfma_f32_32x32x16_bf16(a, bv, acc, 0, 0, 0);
    }
  }
  int ql = qlen[b], kl = klen[b];
  float kkv = kk[b * TT + col];
  float krv = kR[b * TT + col];
  bool cm = col < kl;
  #pragma unroll
  for (int r = 0; r < 16; ++r){
    int row = r0 + (r & 3) + 8 * (r >> 2) + 4 * hi;
    float qqv = qq[b * TT + row];
    float sq = qqv + kkv - 2.f * acc[r];
    float d = sqrtf(fmaxf(sq, 1e-12f));
    bool m = (row < ql) && cm;
    float dm = m ? d : 0.f;
    float pm = m ? fabsf(qR[b * TT + row] - krv) : 0.f;
    Dout[(((size_t)b * TT + row) << 7) + col] = dm;
    inb[(((size_t)b * TT + row) << 7) + col] = pack2bf(dm, pm);
  }
}

// ---------------- conv1: 2ch -> 30ch 5x5 via bf16 MFMA, fp8 out [b][y][x][c32] ----------------
#define C1_ROWW 136
__global__ __launch_bounds__(512, 2) void conv1_mfma_k(const u32* __restrict__ inb,
    const u16* __restrict__ w1c, const float* __restrict__ bias, u8* __restrict__ act1){
  __shared__ u32 ilds[12 * C1_ROWW];
  __shared__ __align__(16) char wlds[5120];
  __shared__ __align__(16) char tr[8 * 4096];
  int yg = blockIdx.x, bb = blockIdx.y;
  int y0 = yg * 8, tid = threadIdx.x;
  {
    const uint4* src = (const uint4*)w1c;
    uint4* dst = (uint4*)wlds;
    for (int i = tid; i < 320; i += 512) dst[i] = src[i];
  }
  for (int i = tid; i < 12 * C1_ROWW; i += 512){
    int r = i / C1_ROWW, xi = i - r * C1_ROWW;
    int gy = y0 - 2 + r, gx = xi - 2;
    u32 v = 0;
    if ((unsigned)gy < 128u && (unsigned)gx < 128u)
      v = inb[(((size_t)bb * 128 + gy) << 7) + gx];
    ilds[r * C1_ROWW + xi] = v;
  }
  __syncthreads();
  int lane = tid & 63, w = tid >> 6;
  int hi = lane >> 5, l31 = lane & 31;
  bf16x8 afr[5];
  #pragma unroll
  for (int dy = 0; dy < 5; ++dy)
    afr[dy] = *(const bf16x8*)(wlds + dy*1024 + (((l31<<5) + (hi<<4)) ^ ((l31&7)<<4)));
  float biasv[16];
  #pragma unroll
  for (int r = 0; r < 16; ++r){
    int oc = (r & 3) + 8*(r >> 2) + 4*hi;
    biasv[r] = (oc < MC) ? bias[oc] : 0.f;
  }
  int wbase = w * 4096;
  #pragma unroll
  for (int t = 0; t < 4; ++t){
    int px = t*32 + l31;
    f32x16 acc;
    #pragma unroll
    for (int r = 0; r < 16; ++r) acc[r] = 0.f;
    #pragma unroll
    for (int dy = 0; dy < 5; ++dy){
      const u32* rp = &ilds[(w + dy)*C1_ROWW + px + hi*4];
      union { u32 uw[4]; bf16x8 v; } ub;
      ub.uw[0] = rp[0]; ub.uw[1] = rp[1]; ub.uw[2] = rp[2]; ub.uw[3] = rp[3];
      acc = __builtin_amdgcn_mfma_f32_32x32x16_bf16(afr[dy], ub.v, acc, 0, 0, 0);
    }
    #pragma unroll
    for (int q = 0; q < 4; ++q){
      float v0 = fmaxf(acc[4*q+0] + biasv[4*q+0], 0.f);
      float v1 = fmaxf(acc[4*q+1] + biasv[4*q+1], 0.f);
      float v2 = fmaxf(acc[4*q+2] + biasv[4*q+2], 0.f);
      float v3 = fmaxf(acc[4*q+3] + biasv[4*q+3], 0.f);
      u32 word = pk_fp8<false>(v0, v1, 0u);
      word = pk_fp8<true>(v2, v3, word);
      int addr = wbase + (((px<<5) + (q<<3) + (hi<<2)) ^ ((px&7)<<3));
      *(u32*)(tr + addr) = word;
    }
  }
  int y = y0 + w;
  #pragma unroll
  for (int p = 0; p < 8; ++p){
    int x = p*16 + (lane >> 2), cg = lane & 3;
    int addr = wbase + (((x<<5) + (cg<<3)) ^ ((x&7)<<3));
    uint2 v = *(const uint2*)(tr + addr);
    *(uint2*)(act1 + ((((size_t)bb*128 + y)*128 + x) << 5) + cg*8) = v;
  }
}

// ---------------- conv2: 30->30 5x5 via fp8 MFMA, weights in regs, swizzled LDS ----------------
#define C2_IN_ROWB 4224                 // 132 px * 32 B
#define C2_SMEM (12*C2_IN_ROWB)         // 50688

__global__ __launch_bounds__(512, 6) void conv2_mfma_k(
    const u8* __restrict__ act1, const u8* __restrict__ w2p,
    const float* __restrict__ bias, u8* __restrict__ act2){
  __shared__ __align__(16) char smem[C2_SMEM];
  int yg = blockIdx.x;          // 0..15
  int bb = blockIdx.y;
  int y0 = yg * 8;
  int tid = threadIdx.x;
  int lane = tid & 63, w = tid >> 6;
  int hi = lane >> 5, l31 = lane & 31;
  // A-frags (weights) straight from global into registers: coalesced, L1/L2-hot
  ll2 aw[25];
  #pragma unroll
  for (int tap = 0; tap < 25; ++tap)
    aw[tap] = *(const ll2*)(w2p + tap*1024 + (l31 << 5) + (hi << 4));
  // stage input rows y0-2 .. y0+9 : [r][x132][ic32] fp8, XOR-swizzled (16B granule)
  for (int i = tid; i < 3168; i += 512){
    int r = i / 264; int t2 = i - r*264; int lx = t2 >> 1; int h = t2 & 1;
    int gy = y0 - 2 + r, gx = lx - 2;
    uint4 v = make_uint4(0,0,0,0);
    if ((unsigned)gy < 128u && (unsigned)gx < 128u)
      v = *(const uint4*)(act1 + ((((size_t)(bb*128 + gy)*128 + gx)) << 5) + (h << 4));
    int boff = ((lx << 5) + (h << 4)) ^ ((lx & 7) << 4);
    *(uint4*)(smem + r*C2_IN_ROWB + boff) = v;
  }
  __syncthreads();
  f32x16 acc[4];
  #pragma unroll
  for (int t = 0; t < 4; ++t)
    #pragma unroll
    for (int r = 0; r < 16; ++r) acc[t][r] = 0.f;
  #pragma unroll
  for (int dy = 0; dy < 5; ++dy){
    const char* rowp = smem + (w + dy)*C2_IN_ROWB;
    #pragma unroll
    for (int dx = 0; dx < 5; ++dx){
      ll2 a = aw[dy*5 + dx];
      #pragma unroll
      for (int t = 0; t < 4; ++t){
        int px2 = t*32 + l31 + dx;
        int boff = ((px2 << 5) + (hi << 4)) ^ ((px2 & 7) << 4);
        ll2 b = *(const ll2*)(rowp + boff);
        acc[t] = __builtin_amdgcn_mfma_f32_32x32x16_fp8_fp8(a.x, b.x, acc[t], 0, 0, 0);
        acc[t] = __builtin_amdgcn_mfma_f32_32x32x16_fp8_fp8(a.y, b.y, acc[t], 0, 0, 0);
      }
    }
  }
  float biasv[16];
  #pragma unroll
  for (int r = 0; r < 16; ++r){
    int oc = (r & 3) + 8*(r >> 2) + 4*hi;
    biasv[r] = (oc < MC) ? bias[oc] : 0.f;
  }
  __syncthreads();   // all reads done before overwriting LDS
  // transpose via LDS (per-wave 4KB region inside dead input area)
  int wbase = w * 4096;
  #pragma unroll
  for (int t = 0; t < 4; ++t){
    int px = t*32 + l31;
    #pragma unroll
    for (int q = 0; q < 4; ++q){
      float v0 = fmaxf(acc[t][4*q+0] + biasv[4*q+0], 0.f);
      float v1 = fmaxf(acc[t][4*q+1] + biasv[4*q+1], 0.f);
      float v2 = fmaxf(acc[t][4*q+2] + biasv[4*q+2], 0.f);
      float v3 = fmaxf(acc[t][4*q+3] + biasv[4*q+3], 0.f);
      u32 word = pk_fp8<false>(v0, v1, 0u);
      word = pk_fp8<true>(v2, v3, word);
      int addr = wbase + (((px<<5) + (q<<3) + (hi<<2)) ^ ((px&7)<<3));
      *(u32*)(smem + addr) = word;
    }
  }
  int y = y0 + w;
  #pragma unroll
  for (int p = 0; p < 8; ++p){
    int x = p*16 + (lane >> 2), cg = lane & 3;
    int addr = wbase + (((x<<5) + (cg<<3)) ^ ((x&7)<<3));
    uint2 v = *(const uint2*)(smem + addr);
    *(uint2*)(act2 + ((((size_t)bb*128 + y)*128 + x) << 5) + cg*8) = v;
  }
}

// ---------------- conv3 + mask + row softmax + A write + row D*A ----------------
__global__ __launch_bounds__(512) void conv3sm_k(const u8* __restrict__ act2,
    const float* __restrict__ w3, const float* __restrict__ b3, const float* __restrict__ Dbuf,
    const int* __restrict__ qlen, const int* __restrict__ klen,
    float* __restrict__ Aout, float* __restrict__ rowsum, int b0){
  __shared__ float wlds[9][32];
  __shared__ float ex0[512], ex2[512];
  __shared__ float redm[8], reds[8], redd[8];
  int i  = blockIdx.x;
  int bb = blockIdx.y;
  int b  = b0 + bb;
  int tid = threadIdx.x;
  for (int idx = tid; idx < 288; idx += 512){
    int tap = idx >> 5, c = idx & 31;
    wlds[tap][c] = (c < MC) ? w3[c * 9 + tap] : 0.f;
  }
  __syncthreads();
  int px = tid >> 2, cg = tid & 3, wv = tid >> 6;
  float T0 = 0.f, T1 = 0.f, T2 = 0.f;
  #pragma unroll
  for (int dy = 0; dy < 3; ++dy){
    int gy = i - 1 + dy;
    uint2 v = make_uint2(0, 0);
    if ((unsigned)gy < 128u)
      v = *(const uint2*)(act2 + ((((size_t)bb*128 + gy)*128 + px) << 5) + cg*8);
    float x[8];
    upk_fp8x4(v.x, x);
    upk_fp8x4(v.y, x + 4);
    const float* w0p = &wlds[dy*3 + 0][cg*8];
    const float* w1p = &wlds[dy*3 + 1][cg*8];
    const float* w2q = &wlds[dy*3 + 2][cg*8];
    #pragma unroll
    for (int c = 0; c < 8; ++c){
      T0 = fmaf(x[c], w0p[c], T0);
      T1 = fmaf(x[c], w1p[c], T1);
      T2 = fmaf(x[c], w2q[c], T2);
    }
  }
  ex0[tid] = T0; ex2[tid] = T2;
  __syncthreads();
  float acc = T1;
  if (px > 0)   acc += ex0[tid - 4];
  if (px < 127) acc += ex2[tid + 4];
  acc += __shfl_xor(acc, 1);
  acc += __shfl_xor(acc, 2);
  acc += b3[0];
  float Dv = Dbuf[(((size_t)b * 128 + i) << 7) + px];
  bool m = (i < qlen[b]) && (px < klen[b]);
  float xv = m ? -(acc + Dv) : -100.f;
  float mx = xv;
  #pragma unroll
  for (int o = 32; o; o >>= 1) mx = fmaxf(mx, __shfl_xor(mx, o));
  if ((tid & 63) == 0) redm[wv] = mx;
  __syncthreads();
  mx = fmaxf(fmaxf(fmaxf(redm[0], redm[1]), fmaxf(redm[2], redm[3])),
             fmaxf(fmaxf(redm[4], redm[5]), fmaxf(redm[6], redm[7])));
  float e = __expf(xv - mx);
  float s  = e;
  float de = Dv * e;
  #pragma unroll
  for (int o = 32; o; o >>= 1){ s += __shfl_xor(s, o); de += __shfl_xor(de, o); }
  if ((tid & 63) == 0){ reds[wv] = s; redd[wv] = de; }
  __syncthreads();
  float s8  = (reds[0] + reds[1]) + (reds[2] + reds[3]) + (reds[4] + reds[5]) + (reds[6] + reds[7]);
  float a = e * 4.0f / s8;
  if (cg == 0) Aout[(((size_t)b * 128 + i) << 7) + px] = a;
  if (tid == 0){
    float d8 = (redd[0] + redd[1]) + (redd[2] + redd[3]) + (redd[4] + redd[5]) + (redd[6] + redd[7]);
    rowsum[b * TT + i] = d8 / s8;
  }
}

// ---------------- dis reduce ----------------
__global__ __launch_bounds__(128) void dis_k(const float* __restrict__ rowsum, float* __restrict__ out){
  int b = blockIdx.x, tid = threadIdx.x;
  float v = rowsum[b * TT + tid];
  #pragma unroll
  for (int o = 32; o; o >>= 1) v += __shfl_xor(v, o);
  __shared__ float red[2];
  if ((tid & 63) == 0) red[tid >> 6] = v;
  __syncthreads();
  if (tid == 0) out[b] = (red[0] + red[1]) * (1.0f / 128.0f);
}

extern "C" void kernel_launch(void* const* d_in, const int* in_sizes, int n_in,
                              void* d_out, int out_size, void* d_ws, size_t ws_size,
                              hipStream_t stream){
  const float* q_seq = (const float*)d_in[0];
  const int*   q_len = (const int*)d_in[1];
  const float* q_R   = (const float*)d_in[2];
  const float* k_seq = (const float*)d_in[3];
  const int*   k_len = (const int*)d_in[4];
  const float* k_R   = (const float*)d_in[5];
  const float* c1w   = (const float*)d_in[6];
  const float* c1b   = (const float*)d_in[7];
  const float* c2w   = (const float*)d_in[8];
  const float* c2b   = (const float*)d_in[9];
  const float* c3w   = (const float*)d_in[10];
  const float* c3b   = (const float*)d_in[11];
  float* out = (float*)d_out;

  char* base = (char*)d_ws;
  size_t off = 0;
  auto take = [&](size_t bytes)->char*{
    char* p = base + off;
    off = (off + bytes + 255) & ~(size_t)255;
    return p;
  };
  float* Dbuf   = (float*)take((size_t)NB * TT * TT * 4);
  float* qq     = (float*)take((size_t)NB * TT * 4);
  float* kkn    = (float*)take((size_t)NB * TT * 4);
  float* rowsum = (float*)take((size_t)NB * TT * 4);
  u32*   inb    = (u32*)  take((size_t)NB * TT * TT * 4);
  u8*    w2p    = (u8*)   take(25 * 1024);
  u16*   w1c    = (u16*)  take(5 * 1024);
  u16*   qb16   = (u16*)  take((size_t)NB * TT * DK * 2);
  u16*   kb16   = (u16*)  take((size_t)NB * TT * DK * 2);
  size_t fixed = off;
  int BCH = 64;
  while (BCH > 1 && fixed + (size_t)BCH * TT * TT * 64 + 1024 > ws_size) BCH >>= 1;
  u8* act1 = (u8*)take((size_t)BCH * TT * TT * 32);
  u8* act2 = (u8*)take((size_t)BCH * TT * TT * 32);

  prep_w_k<<<26, 256, 0, stream>>>(c2w, c1w, w2p, w1c);
  row_norms_k<<<4096, 256, 0, stream>>>(q_seq, k_seq, qq, kkn, qb16, kb16);
  cdist_mfma_k<<<dim3(4, NB), 256, 0, stream>>>(qb16, kb16, qq, kkn, q_len, k_len, q_R, k_R, Dbuf, inb);
  for (int b0 = 0; b0 < NB; b0 += BCH){
    int nb = BCH;
    conv1_mfma_k<<<dim3(16, nb), 512, 0, stream>>>(inb + (size_t)b0 * TT * TT, w1c, c1b, act1);
    conv2_mfma_k<<<dim3(16, nb), 512, 0, stream>>>(act1, w2p, c2b, act2);
    conv3sm_k<<<dim3(TT, nb), 512, 0, stream>>>(act2, c3w, c3b, Dbuf, q_len, k_len, out, rowsum, b0);
  }
  dis_k<<<NB, 128, 0, stream>>>(rowsum, out + (size_t)NB * TT * TT);
}

// Round 10
// 128.389 us; speedup vs baseline: 3.4065x; 3.4065x over previous
//
#include <hip/hip_runtime.h>
#include <hip/hip_bf16.h>
#include <stdint.h>

using u16 = unsigned short;
using u32 = unsigned int;
using u8  = unsigned char;

#define NB 64
#define TT 128
#define DK 768
#define MC 30

typedef float f32x16 __attribute__((ext_vector_type(16)));
typedef __bf16 bf16x8 __attribute__((ext_vector_type(8)));
typedef long long ll;
typedef __attribute__((ext_vector_type(2))) ll ll2;

__device__ inline void unpack2(u32 u, float& lo, float& hi){
  union{u32 i; float f;} a, b; a.i = u << 16; b.i = u & 0xFFFF0000u; lo = a.f; hi = b.f;
}
__device__ inline u16 f2bf(float f){
  union{u32 i; float f;} v; v.f = f;
  u32 r = v.i + 0x7FFFu + ((v.i >> 16) & 1u);
  return (u16)(r >> 16);
}
__device__ inline u32 pack2bf(float a, float b){ return (u32)f2bf(a) | ((u32)f2bf(b) << 16); }

// ---------------- fp8 e4m3fn pack/unpack helpers ----------------
#if __has_builtin(__builtin_amdgcn_cvt_pk_fp8_f32)
template<bool HIW>
__device__ inline u32 pk_fp8(float a, float b, u32 old){
  return (u32)__builtin_amdgcn_cvt_pk_fp8_f32(a, b, (int)old, HIW);
}
#else
__device__ inline u8 f2fp8_1(float f){
  union{float f; u32 u;} v; v.f = f;
  u32 s = (v.u >> 24) & 0x80u;
  u32 abs = v.u & 0x7fffffffu;
  if (abs < 0x3c800000u){
    float sc = fabsf(f) * 512.0f;
    int m = (int)rintf(sc);
    return (u8)(s | (u32)m);
  }
  u32 e8 = abs >> 23; u32 mant = abs & 0x7fffffu;
  u32 m3 = mant >> 20; u32 rest = mant & 0xfffffu;
  u32 rb = (rest > 0x80000u) || (rest == 0x80000u && (m3 & 1u));
  m3 += rb;
  u32 E = e8 - 120u;
  if (m3 == 8u){ m3 = 0u; E += 1u; }
  if (E >= 16u || (E == 15u && m3 == 7u)) return (u8)(s | 0x7Eu);
  return (u8)(s | (E << 3) | m3);
}
template<bool HIW>
__device__ inline u32 pk_fp8(float a, float b, u32 old){
  u32 w = (u32)f2fp8_1(a) | ((u32)f2fp8_1(b) << 8);
  return HIW ? ((old & 0x0000FFFFu) | (w << 16)) : ((old & 0xFFFF0000u) | w);
}
#endif

#if __has_builtin(__builtin_amdgcn_cvt_pk_f32_fp8)
__device__ inline void upk_fp8x4(u32 w, float* x){
  auto a0 = __builtin_amdgcn_cvt_pk_f32_fp8((int)w, false);
  auto a1 = __builtin_amdgcn_cvt_pk_f32_fp8((int)w, true);
  x[0] = a0[0]; x[1] = a0[1]; x[2] = a1[0]; x[3] = a1[1];
}
#else
__device__ inline float fp8_1(u32 byte){
  u32 s = (byte & 0x80u) << 24;
  u32 E = (byte >> 3) & 15u, M = byte & 7u;
  union{u32 u; float f;} v;
  if (E == 0){ v.f = (float)M * (1.0f/512.0f); v.u |= s; }
  else v.u = s | ((E + 120u) << 23) | (M << 20);
  return v.f;
}
__device__ inline void upk_fp8x4(u32 w, float* x){
  x[0] = fp8_1(w & 255u); x[1] = fp8_1((w >> 8) & 255u);
  x[2] = fp8_1((w >> 16) & 255u); x[3] = fp8_1(w >> 24);
}
#endif

// ---------------- weight prep ----------------
// w2p: fp8 [tap][oc32][ic32] linear, 1024 B per tap
// w1c: bf16 MFMA A-frag table [dy][oc32][k16], k = dx*2 + c (dx>=5 zero), swizzled
__global__ __launch_bounds__(256) void prep_w_k(const float* __restrict__ w2,
    const float* __restrict__ w1, u8* __restrict__ w2p, u16* __restrict__ w1c){
  int bidx = blockIdx.x;
  if (bidx < 25){
    int tap = bidx;
    int i = threadIdx.x;
    int oc = i >> 3, q = i & 7, ic0 = q * 4;
    float v[4];
    #pragma unroll
    for (int j = 0; j < 4; ++j)
      v[j] = (oc < MC && ic0 + j < MC) ? w2[(oc*MC + ic0 + j)*25 + tap] : 0.f;
    u32 w = pk_fp8<false>(v[0], v[1], 0u);
    w = pk_fp8<true>(v[2], v[3], w);
    *(u32*)(w2p + tap*1024 + oc*32 + q*4) = w;
  } else {
    for (int i = threadIdx.x; i < 2560; i += 256){
      int dy = i >> 9; int rem = i & 511; int oc = rem >> 4; int k = rem & 15;
      int dx = k >> 1, c = k & 1;
      float v = (oc < MC && dx < 5) ? w1[(oc*2 + c)*25 + dy*5 + dx] : 0.f;
      int byteoff = dy*1024 + (((oc<<5) + (k<<1)) ^ ((oc&7)<<4));
      *(u16*)((char*)w1c + byteoff) = f2bf(v);
    }
  }
}

// ---------------- kernel 1: row norms + bf16 conversion ----------------
__global__ __launch_bounds__(256) void row_norms_k(const float* __restrict__ q, const float* __restrict__ k,
    float* __restrict__ qq, float* __restrict__ kk,
    u16* __restrict__ qb16, u16* __restrict__ kb16){
  int wave = blockIdx.x * 4 + (threadIdx.x >> 6);
  int lane = threadIdx.x & 63;
  const float* src; float* dst; u16* bdst; int row;
  if (wave < NB * TT) { src = q; dst = qq; bdst = qb16; row = wave; }
  else                { src = k; dst = kk; bdst = kb16; row = wave - NB * TT; }
  const float4* p = (const float4*)(src + (size_t)row * DK + lane * 12);
  u16* ob = bdst + (size_t)row * DK + lane * 12;
  float s = 0.f;
  #pragma unroll
  for (int t = 0; t < 3; ++t){
    float4 v = p[t];
    s += v.x*v.x + v.y*v.y + v.z*v.z + v.w*v.w;
    uint2 st; st.x = pack2bf(v.x, v.y); st.y = pack2bf(v.z, v.w);
    *(uint2*)(ob + t*4) = st;
  }
  #pragma unroll
  for (int o = 32; o; o >>= 1) s += __shfl_xor(s, o);
  if (lane == 0) dst[row] = s;
}

// ---------------- kernel 2: cdist via bf16 MFMA + P + mask ----------------
// inb output: u32 per (b,y,x): lo = bf16(D), hi = bf16(P)
__global__ __launch_bounds__(256) void cdist_mfma_k(
    const u16* __restrict__ Qb16, const u16* __restrict__ Kb16,
    const float* __restrict__ qq, const float* __restrict__ kk,
    const int* __restrict__ qlen, const int* __restrict__ klen,
    const float* __restrict__ qR, const float* __restrict__ kR,
    float* __restrict__ Dout, u32* __restrict__ inb){
  __shared__ __align__(16) char qs[32 * 1536];    // [32 rows][768 k] bf16, swizzled
  __shared__ __align__(16) char ksm[128 * 256];   // [128 cols][128 k] bf16, swizzled
  int rt = blockIdx.x;
  int b  = blockIdx.y;
  int r0 = rt * 32;
  int tid = threadIdx.x;
  const u16* Qg = Qb16 + ((size_t)b * TT + r0) * DK;
  const u16* Kg = Kb16 + (size_t)b * TT * DK;
  for (int idx = tid; idx < 3072; idx += 256){
    int row = idx / 96, ch = idx - row * 96;
    uint4 v = *(const uint4*)(Qg + row * DK + ch * 8);
    *(uint4*)(qs + row * 1536 + ((ch * 16) ^ ((row & 7) << 4))) = v;
  }
  int lane = tid & 63, w = tid >> 6;
  int hi = lane >> 5, l31 = lane & 31;
  int col = w * 32 + l31;
  f32x16 acc;
  #pragma unroll
  for (int r = 0; r < 16; ++r) acc[r] = 0.f;
  for (int kc = 0; kc < DK; kc += 128){
    __syncthreads();
    for (int idx = tid; idx < 2048; idx += 256){
      int c = idx >> 4, j = idx & 15;
      uint4 v = *(const uint4*)(Kg + c * DK + kc + j * 8);
      *(uint4*)(ksm + c * 256 + ((j * 16) ^ ((c & 7) << 4))) = v;
    }
    __syncthreads();
    #pragma unroll
    for (int k8 = 0; k8 < 8; ++k8){
      bf16x8 a  = *(const bf16x8*)(qs  + l31 * 1536 + (((kc + k8*16 + hi*8) * 2) ^ ((l31 & 7) << 4)));
      bf16x8 bv = *(const bf16x8*)(ksm + col * 256  + (((k8*16 + hi*8) * 2) ^ ((col & 7) << 4)));
      acc = __builtin_amdgcn_mfma_f32_32x32x16_bf16(a, bv, acc, 0, 0, 0);
    }
  }
  int ql = qlen[b], kl = klen[b];
  float kkv = kk[b * TT + col];
  float krv = kR[b * TT + col];
  bool cm = col < kl;
  #pragma unroll
  for (int r = 0; r < 16; ++r){
    int row = r0 + (r & 3) + 8 * (r >> 2) + 4 * hi;
    float qqv = qq[b * TT + row];
    float sq = qqv + kkv - 2.f * acc[r];
    float d = sqrtf(fmaxf(sq, 1e-12f));
    bool m = (row < ql) && cm;
    float dm = m ? d : 0.f;
    float pm = m ? fabsf(qR[b * TT + row] - krv) : 0.f;
    Dout[(((size_t)b * TT + row) << 7) + col] = dm;
    inb[(((size_t)b * TT + row) << 7) + col] = pack2bf(dm, pm);
  }
}

// ---------------- conv1: 2ch -> 30ch 5x5 via bf16 MFMA, fp8 out [b][y][x][c32] ----------------
#define C1_ROWW 136
__global__ __launch_bounds__(512, 2) void conv1_mfma_k(const u32* __restrict__ inb,
    const u16* __restrict__ w1c, const float* __restrict__ bias, u8* __restrict__ act1){
  __shared__ u32 ilds[12 * C1_ROWW];
  __shared__ __align__(16) char wlds[5120];
  __shared__ __align__(16) char tr[8 * 4096];
  int yg = blockIdx.x, bb = blockIdx.y;
  int y0 = yg * 8, tid = threadIdx.x;
  {
    const uint4* src = (const uint4*)w1c;
    uint4* dst = (uint4*)wlds;
    for (int i = tid; i < 320; i += 512) dst[i] = src[i];
  }
  for (int i = tid; i < 12 * C1_ROWW; i += 512){
    int r = i / C1_ROWW, xi = i - r * C1_ROWW;
    int gy = y0 - 2 + r, gx = xi - 2;
    u32 v = 0;
    if ((unsigned)gy < 128u && (unsigned)gx < 128u)
      v = inb[(((size_t)bb * 128 + gy) << 7) + gx];
    ilds[r * C1_ROWW + xi] = v;
  }
  __syncthreads();
  int lane = tid & 63, w = tid >> 6;
  int hi = lane >> 5, l31 = lane & 31;
  bf16x8 afr[5];
  #pragma unroll
  for (int dy = 0; dy < 5; ++dy)
    afr[dy] = *(const bf16x8*)(wlds + dy*1024 + (((l31<<5) + (hi<<4)) ^ ((l31&7)<<4)));
  float biasv[16];
  #pragma unroll
  for (int r = 0; r < 16; ++r){
    int oc = (r & 3) + 8*(r >> 2) + 4*hi;
    biasv[r] = (oc < MC) ? bias[oc] : 0.f;
  }
  int wbase = w * 4096;
  #pragma unroll
  for (int t = 0; t < 4; ++t){
    int px = t*32 + l31;
    f32x16 acc;
    #pragma unroll
    for (int r = 0; r < 16; ++r) acc[r] = 0.f;
    #pragma unroll
    for (int dy = 0; dy < 5; ++dy){
      const u32* rp = &ilds[(w + dy)*C1_ROWW + px + hi*4];
      union { u32 uw[4]; bf16x8 v; } ub;
      ub.uw[0] = rp[0]; ub.uw[1] = rp[1]; ub.uw[2] = rp[2]; ub.uw[3] = rp[3];
      acc = __builtin_amdgcn_mfma_f32_32x32x16_bf16(afr[dy], ub.v, acc, 0, 0, 0);
    }
    #pragma unroll
    for (int q = 0; q < 4; ++q){
      float v0 = fmaxf(acc[4*q+0] + biasv[4*q+0], 0.f);
      float v1 = fmaxf(acc[4*q+1] + biasv[4*q+1], 0.f);
      float v2 = fmaxf(acc[4*q+2] + biasv[4*q+2], 0.f);
      float v3 = fmaxf(acc[4*q+3] + biasv[4*q+3], 0.f);
      u32 word = pk_fp8<false>(v0, v1, 0u);
      word = pk_fp8<true>(v2, v3, word);
      int addr = wbase + (((px<<5) + (q<<3) + (hi<<2)) ^ ((px&7)<<3));
      *(u32*)(tr + addr) = word;
    }
  }
  int y = y0 + w;
  #pragma unroll
  for (int p = 0; p < 8; ++p){
    int x = p*16 + (lane >> 2), cg = lane & 3;
    int addr = wbase + (((x<<5) + (cg<<3)) ^ ((x&7)<<3));
    uint2 v = *(const uint2*)(tr + addr);
    *(uint2*)(act1 + ((((size_t)bb*128 + y)*128 + x) << 5) + cg*8) = v;
  }
}

// ---------------- conv2: 30->30 5x5 via fp8 MFMA, fp8 in / fp8 out (round-8 proven) ----------------
#define C2_IN_ROWB 4224                 // 132 px * 32 B
#define C2_IN_BYTES (12*C2_IN_ROWB)     // 50688
#define C2_W_OFF C2_IN_BYTES
#define C2_SMEM (C2_W_OFF + 25*1024)    // 76288

__global__ __launch_bounds__(512, 4) void conv2_mfma_k(
    const u8* __restrict__ act1, const u8* __restrict__ w2p,
    const float* __restrict__ bias, u8* __restrict__ act2){
  __shared__ __align__(16) char smem[C2_SMEM];
  int yg = blockIdx.x;          // 0..15
  int bb = blockIdx.y;
  int y0 = yg * 8;
  int tid = threadIdx.x;
  {
    const uint4* src = (const uint4*)w2p;
    uint4* dst = (uint4*)(smem + C2_W_OFF);
    for (int i = tid; i < 1600; i += 512) dst[i] = src[i];
  }
  for (int i = tid; i < 3168; i += 512){
    int r = i / 264; int t2 = i - r*264; int lx = t2 >> 1; int h = t2 & 1;
    int gy = y0 - 2 + r, gx = lx - 2;
    uint4 v = make_uint4(0,0,0,0);
    if ((unsigned)gy < 128u && (unsigned)gx < 128u)
      v = *(const uint4*)(act1 + ((((size_t)(bb*128 + gy)*128 + gx)) << 5) + (h << 4));
    *(uint4*)(smem + r*C2_IN_ROWB + (lx << 5) + (h << 4)) = v;
  }
  __syncthreads();
  int lane = tid & 63, w = tid >> 6;
  int hi = lane >> 5, l31 = lane & 31;
  int aBase = C2_W_OFF + (l31 << 5) + (hi << 4);
  int bBase = (l31 << 5) + (hi << 4);
  f32x16 acc[4];
  #pragma unroll
  for (int t = 0; t < 4; ++t)
    #pragma unroll
    for (int r = 0; r < 16; ++r) acc[t][r] = 0.f;
  #pragma unroll
  for (int dy = 0; dy < 5; ++dy){
    const char* rowp = smem + (w + dy)*C2_IN_ROWB + bBase;
    #pragma unroll
    for (int dx = 0; dx < 5; ++dx){
      ll2 a = *(const ll2*)(smem + aBase + (dy*5 + dx)*1024);
      #pragma unroll
      for (int t = 0; t < 4; ++t){
        ll2 b = *(const ll2*)(rowp + (t*32 + dx)*32);
        acc[t] = __builtin_amdgcn_mfma_f32_32x32x16_fp8_fp8(a.x, b.x, acc[t], 0, 0, 0);
        acc[t] = __builtin_amdgcn_mfma_f32_32x32x16_fp8_fp8(a.y, b.y, acc[t], 0, 0, 0);
      }
    }
  }
  float biasv[16];
  #pragma unroll
  for (int r = 0; r < 16; ++r){
    int oc = (r & 3) + 8*(r >> 2) + 4*hi;
    biasv[r] = (oc < MC) ? bias[oc] : 0.f;
  }
  __syncthreads();
  int wbase = w * 8192;
  #pragma unroll
  for (int t = 0; t < 4; ++t){
    int px = t*32 + l31;
    #pragma unroll
    for (int q = 0; q < 4; ++q){
      float v0 = fmaxf(acc[t][4*q+0] + biasv[4*q+0], 0.f);
      float v1 = fmaxf(acc[t][4*q+1] + biasv[4*q+1], 0.f);
      float v2 = fmaxf(acc[t][4*q+2] + biasv[4*q+2], 0.f);
      float v3 = fmaxf(acc[t][4*q+3] + biasv[4*q+3], 0.f);
      u32 word = pk_fp8<false>(v0, v1, 0u);
      word = pk_fp8<true>(v2, v3, word);
      int addr = wbase + (((px<<5) + (q<<3) + (hi<<2)) ^ ((px&7)<<3));
      *(u32*)(smem + addr) = word;
    }
  }
  int y = y0 + w;
  #pragma unroll
  for (int p = 0; p < 8; ++p){
    int x = p*16 + (lane >> 2), cg = lane & 3;
    int addr = wbase + (((x<<5) + (cg<<3)) ^ ((x&7)<<3));
    uint2 v = *(const uint2*)(smem + addr);
    *(uint2*)(act2 + ((((size_t)bb*128 + y)*128 + x) << 5) + cg*8) = v;
  }
}

// ---------------- conv3 + mask + row softmax + A write + row D*A ----------------
__global__ __launch_bounds__(512) void conv3sm_k(const u8* __restrict__ act2,
    const float* __restrict__ w3, const float* __restrict__ b3, const float* __restrict__ Dbuf,
    const int* __restrict__ qlen, const int* __restrict__ klen,
    float* __restrict__ Aout, float* __restrict__ rowsum, int b0){
  __shared__ float wlds[9][32];
  __shared__ float ex0[512], ex2[512];
  __shared__ float redm[8], reds[8], redd[8];
  int i  = blockIdx.x;
  int bb = blockIdx.y;
  int b  = b0 + bb;
  int tid = threadIdx.x;
  for (int idx = tid; idx < 288; idx += 512){
    int tap = idx >> 5, c = idx & 31;
    wlds[tap][c] = (c < MC) ? w3[c * 9 + tap] : 0.f;
  }
  __syncthreads();
  int px = tid >> 2, cg = tid & 3, wv = tid >> 6;
  float T0 = 0.f, T1 = 0.f, T2 = 0.f;
  #pragma unroll
  for (int dy = 0; dy < 3; ++dy){
    int gy = i - 1 + dy;
    uint2 v = make_uint2(0, 0);
    if ((unsigned)gy < 128u)
      v = *(const uint2*)(act2 + ((((size_t)bb*128 + gy)*128 + px) << 5) + cg*8);
    float x[8];
    upk_fp8x4(v.x, x);
    upk_fp8x4(v.y, x + 4);
    const float* w0p = &wlds[dy*3 + 0][cg*8];
    const float* w1p = &wlds[dy*3 + 1][cg*8];
    const float* w2q = &wlds[dy*3 + 2][cg*8];
    #pragma unroll
    for (int c = 0; c < 8; ++c){
      T0 = fmaf(x[c], w0p[c], T0);
      T1 = fmaf(x[c], w1p[c], T1);
      T2 = fmaf(x[c], w2q[c], T2);
    }
  }
  ex0[tid] = T0; ex2[tid] = T2;
  __syncthreads();
  float acc = T1;
  if (px > 0)   acc += ex0[tid - 4];
  if (px < 127) acc += ex2[tid + 4];
  acc += __shfl_xor(acc, 1);
  acc += __shfl_xor(acc, 2);
  acc += b3[0];
  float Dv = Dbuf[(((size_t)b * 128 + i) << 7) + px];
  bool m = (i < qlen[b]) && (px < klen[b]);
  float xv = m ? -(acc + Dv) : -100.f;
  float mx = xv;
  #pragma unroll
  for (int o = 32; o; o >>= 1) mx = fmaxf(mx, __shfl_xor(mx, o));
  if ((tid & 63) == 0) redm[wv] = mx;
  __syncthreads();
  mx = fmaxf(fmaxf(fmaxf(redm[0], redm[1]), fmaxf(redm[2], redm[3])),
             fmaxf(fmaxf(redm[4], redm[5]), fmaxf(redm[6], redm[7])));
  float e = __expf(xv - mx);
  float s  = e;
  float de = Dv * e;
  #pragma unroll
  for (int o = 32; o; o >>= 1){ s += __shfl_xor(s, o); de += __shfl_xor(de, o); }
  if ((tid & 63) == 0){ reds[wv] = s; redd[wv] = de; }
  __syncthreads();
  float s8  = (reds[0] + reds[1]) + (reds[2] + reds[3]) + (reds[4] + reds[5]) + (reds[6] + reds[7]);
  float a = e * 4.0f / s8;
  if (cg == 0) Aout[(((size_t)b * 128 + i) << 7) + px] = a;
  if (tid == 0){
    float d8 = (redd[0] + redd[1]) + (redd[2] + redd[3]) + (redd[4] + redd[5]) + (redd[6] + redd[7]);
    rowsum[b * TT + i] = d8 / s8;
  }
}

// ---------------- dis reduce ----------------
__global__ __launch_bounds__(128) void dis_k(const float* __restrict__ rowsum, float* __restrict__ out){
  int b = blockIdx.x, tid = threadIdx.x;
  float v = rowsum[b * TT + tid];
  #pragma unroll
  for (int o = 32; o; o >>= 1) v += __shfl_xor(v, o);
  __shared__ float red[2];
  if ((tid & 63) == 0) red[tid >> 6] = v;
  __syncthreads();
  if (tid == 0) out[b] = (red[0] + red[1]) * (1.0f / 128.0f);
}

extern "C" void kernel_launch(void* const* d_in, const int* in_sizes, int n_in,
                              void* d_out, int out_size, void* d_ws, size_t ws_size,
                              hipStream_t stream){
  const float* q_seq = (const float*)d_in[0];
  const int*   q_len = (const int*)d_in[1];
  const float* q_R   = (const float*)d_in[2];
  const float* k_seq = (const float*)d_in[3];
  const int*   k_len = (const int*)d_in[4];
  const float* k_R   = (const float*)d_in[5];
  const float* c1w   = (const float*)d_in[6];
  const float* c1b   = (const float*)d_in[7];
  const float* c2w   = (const float*)d_in[8];
  const float* c2b   = (const float*)d_in[9];
  const float* c3w   = (const float*)d_in[10];
  const float* c3b   = (const float*)d_in[11];
  float* out = (float*)d_out;

  char* base = (char*)d_ws;
  size_t off = 0;
  auto take = [&](size_t bytes)->char*{
    char* p = base + off;
    off = (off + bytes + 255) & ~(size_t)255;
    return p;
  };
  float* Dbuf   = (float*)take((size_t)NB * TT * TT * 4);
  float* qq     = (float*)take((size_t)NB * TT * 4);
  float* kkn    = (float*)take((size_t)NB * TT * 4);
  float* rowsum = (float*)take((size_t)NB * TT * 4);
  u32*   inb    = (u32*)  take((size_t)NB * TT * TT * 4);
  u8*    w2p    = (u8*)   take(25 * 1024);
  u16*   w1c    = (u16*)  take(5 * 1024);
  u16*   qb16   = (u16*)  take((size_t)NB * TT * DK * 2);
  u16*   kb16   = (u16*)  take((size_t)NB * TT * DK * 2);
  size_t fixed = off;
  int BCH = 64;
  while (BCH > 1 && fixed + (size_t)BCH * TT * TT * 64 + 1024 > ws_size) BCH >>= 1;
  u8* act1 = (u8*)take((size_t)BCH * TT * TT * 32);
  u8* act2 = (u8*)take((size_t)BCH * TT * TT * 32);

  prep_w_k<<<26, 256, 0, stream>>>(c2w, c1w, w2p, w1c);
  row_norms_k<<<4096, 256, 0, stream>>>(q_seq, k_seq, qq, kkn, qb16, kb16);
  cdist_mfma_k<<<dim3(4, NB), 256, 0, stream>>>(qb16, kb16, qq, kkn, q_len, k_len, q_R, k_R, Dbuf, inb);
  for (int b0 = 0; b0 < NB; b0 += BCH){
    int nb = BCH;
    conv1_mfma_k<<<dim3(16, nb), 512, 0, stream>>>(inb + (size_t)b0 * TT * TT, w1c, c1b, act1);
    conv2_mfma_k<<<dim3(16, nb), 512, 0, stream>>>(act1, w2p, c2b, act2);
    conv3sm_k<<<dim3(TT, nb), 512, 0, stream>>>(act2, c3w, c3b, Dbuf, q_len, k_len, out, rowsum, b0);
  }
  dis_k<<<NB, 128, 0, stream>>>(rowsum, out + (size_t)NB * TT * TT);
}

// Round 11
// 127.718 us; speedup vs baseline: 3.4244x; 1.0053x over previous
//
#include <hip/hip_runtime.h>
#include <hip/hip_bf16.h>
#include <stdint.h>

using u16 = unsigned short;
using u32 = unsigned int;
using u8  = unsigned char;

#define NB 64
#define TT 128
#define DK 768
#define MC 30

typedef float f32x16 __attribute__((ext_vector_type(16)));
typedef __bf16 bf16x8 __attribute__((ext_vector_type(8)));
typedef long long ll;
typedef __attribute__((ext_vector_type(2))) ll ll2;

__device__ inline void unpack2(u32 u, float& lo, float& hi){
  union{u32 i; float f;} a, b; a.i = u << 16; b.i = u & 0xFFFF0000u; lo = a.f; hi = b.f;
}
__device__ inline u16 f2bf(float f){
  union{u32 i; float f;} v; v.f = f;
  u32 r = v.i + 0x7FFFu + ((v.i >> 16) & 1u);
  return (u16)(r >> 16);
}
__device__ inline u32 pack2bf(float a, float b){ return (u32)f2bf(a) | ((u32)f2bf(b) << 16); }

// ---------------- fp8 e4m3fn pack/unpack helpers ----------------
#if __has_builtin(__builtin_amdgcn_cvt_pk_fp8_f32)
template<bool HIW>
__device__ inline u32 pk_fp8(float a, float b, u32 old){
  return (u32)__builtin_amdgcn_cvt_pk_fp8_f32(a, b, (int)old, HIW);
}
#else
__device__ inline u8 f2fp8_1(float f){
  union{float f; u32 u;} v; v.f = f;
  u32 s = (v.u >> 24) & 0x80u;
  u32 abs = v.u & 0x7fffffffu;
  if (abs < 0x3c800000u){
    float sc = fabsf(f) * 512.0f;
    int m = (int)rintf(sc);
    return (u8)(s | (u32)m);
  }
  u32 e8 = abs >> 23; u32 mant = abs & 0x7fffffu;
  u32 m3 = mant >> 20; u32 rest = mant & 0xfffffu;
  u32 rb = (rest > 0x80000u) || (rest == 0x80000u && (m3 & 1u));
  m3 += rb;
  u32 E = e8 - 120u;
  if (m3 == 8u){ m3 = 0u; E += 1u; }
  if (E >= 16u || (E == 15u && m3 == 7u)) return (u8)(s | 0x7Eu);
  return (u8)(s | (E << 3) | m3);
}
template<bool HIW>
__device__ inline u32 pk_fp8(float a, float b, u32 old){
  u32 w = (u32)f2fp8_1(a) | ((u32)f2fp8_1(b) << 8);
  return HIW ? ((old & 0x0000FFFFu) | (w << 16)) : ((old & 0xFFFF0000u) | w);
}
#endif

#if __has_builtin(__builtin_amdgcn_cvt_pk_f32_fp8)
__device__ inline void upk_fp8x4(u32 w, float* x){
  auto a0 = __builtin_amdgcn_cvt_pk_f32_fp8((int)w, false);
  auto a1 = __builtin_amdgcn_cvt_pk_f32_fp8((int)w, true);
  x[0] = a0[0]; x[1] = a0[1]; x[2] = a1[0]; x[3] = a1[1];
}
#else
__device__ inline float fp8_1(u32 byte){
  u32 s = (byte & 0x80u) << 24;
  u32 E = (byte >> 3) & 15u, M = byte & 7u;
  union{u32 u; float f;} v;
  if (E == 0){ v.f = (float)M * (1.0f/512.0f); v.u |= s; }
  else v.u = s | ((E + 120u) << 23) | (M << 20);
  return v.f;
}
__device__ inline void upk_fp8x4(u32 w, float* x){
  x[0] = fp8_1(w & 255u); x[1] = fp8_1((w >> 8) & 255u);
  x[2] = fp8_1((w >> 16) & 255u); x[3] = fp8_1(w >> 24);
}
#endif

// ---------------- weight prep ----------------
// w2p: fp8 [tap][oc32][ic32], intra-page bytes pre-swizzled with ^((oc&7)<<4)
//      so conv2's A-fragment reads are bank-spread.
// w1c: bf16 MFMA A-frag table [dy][oc32][k16], k = dx*2 + c (dx>=5 zero), swizzled
__global__ __launch_bounds__(256) void prep_w_k(const float* __restrict__ w2,
    const float* __restrict__ w1, u8* __restrict__ w2p, u16* __restrict__ w1c){
  int bidx = blockIdx.x;
  if (bidx < 25){
    int tap = bidx;
    int i = threadIdx.x;
    int oc = i >> 3, q = i & 7, ic0 = q * 4;
    float v[4];
    #pragma unroll
    for (int j = 0; j < 4; ++j)
      v[j] = (oc < MC && ic0 + j < MC) ? w2[(oc*MC + ic0 + j)*25 + tap] : 0.f;
    u32 w = pk_fp8<false>(v[0], v[1], 0u);
    w = pk_fp8<true>(v[2], v[3], w);
    int lo = ((oc << 5) + (q << 2)) ^ ((oc & 7) << 4);
    *(u32*)(w2p + tap*1024 + lo) = w;
  } else {
    for (int i = threadIdx.x; i < 2560; i += 256){
      int dy = i >> 9; int rem = i & 511; int oc = rem >> 4; int k = rem & 15;
      int dx = k >> 1, c = k & 1;
      float v = (oc < MC && dx < 5) ? w1[(oc*2 + c)*25 + dy*5 + dx] : 0.f;
      int byteoff = dy*1024 + (((oc<<5) + (k<<1)) ^ ((oc&7)<<4));
      *(u16*)((char*)w1c + byteoff) = f2bf(v);
    }
  }
}

// ---------------- kernel 1: row norms + bf16 conversion ----------------
__global__ __launch_bounds__(256) void row_norms_k(const float* __restrict__ q, const float* __restrict__ k,
    float* __restrict__ qq, float* __restrict__ kk,
    u16* __restrict__ qb16, u16* __restrict__ kb16){
  int wave = blockIdx.x * 4 + (threadIdx.x >> 6);
  int lane = threadIdx.x & 63;
  const float* src; float* dst; u16* bdst; int row;
  if (wave < NB * TT) { src = q; dst = qq; bdst = qb16; row = wave; }
  else                { src = k; dst = kk; bdst = kb16; row = wave - NB * TT; }
  const float4* p = (const float4*)(src + (size_t)row * DK + lane * 12);
  u16* ob = bdst + (size_t)row * DK + lane * 12;
  float s = 0.f;
  #pragma unroll
  for (int t = 0; t < 3; ++t){
    float4 v = p[t];
    s += v.x*v.x + v.y*v.y + v.z*v.z + v.w*v.w;
    uint2 st; st.x = pack2bf(v.x, v.y); st.y = pack2bf(v.z, v.w);
    *(uint2*)(ob + t*4) = st;
  }
  #pragma unroll
  for (int o = 32; o; o >>= 1) s += __shfl_xor(s, o);
  if (lane == 0) dst[row] = s;
}

// ---------------- kernel 2: cdist via bf16 MFMA + P + mask ----------------
// inb output: u32 per (b,y,x): lo = bf16(D), hi = bf16(P)
__global__ __launch_bounds__(256) void cdist_mfma_k(
    const u16* __restrict__ Qb16, const u16* __restrict__ Kb16,
    const float* __restrict__ qq, const float* __restrict__ kk,
    const int* __restrict__ qlen, const int* __restrict__ klen,
    const float* __restrict__ qR, const float* __restrict__ kR,
    float* __restrict__ Dout, u32* __restrict__ inb){
  __shared__ __align__(16) char qs[32 * 1536];    // [32 rows][768 k] bf16, swizzled
  __shared__ __align__(16) char ksm[128 * 256];   // [128 cols][128 k] bf16, swizzled
  int rt = blockIdx.x;
  int b  = blockIdx.y;
  int r0 = rt * 32;
  int tid = threadIdx.x;
  const u16* Qg = Qb16 + ((size_t)b * TT + r0) * DK;
  const u16* Kg = Kb16 + (size_t)b * TT * DK;
  for (int idx = tid; idx < 3072; idx += 256){
    int row = idx / 96, ch = idx - row * 96;
    uint4 v = *(const uint4*)(Qg + row * DK + ch * 8);
    *(uint4*)(qs + row * 1536 + ((ch * 16) ^ ((row & 7) << 4))) = v;
  }
  int lane = tid & 63, w = tid >> 6;
  int hi = lane >> 5, l31 = lane & 31;
  int col = w * 32 + l31;
  f32x16 acc;
  #pragma unroll
  for (int r = 0; r < 16; ++r) acc[r] = 0.f;
  for (int kc = 0; kc < DK; kc += 128){
    __syncthreads();
    for (int idx = tid; idx < 2048; idx += 256){
      int c = idx >> 4, j = idx & 15;
      uint4 v = *(const uint4*)(Kg + c * DK + kc + j * 8);
      *(uint4*)(ksm + c * 256 + ((j * 16) ^ ((c & 7) << 4))) = v;
    }
    __syncthreads();
    #pragma unroll
    for (int k8 = 0; k8 < 8; ++k8){
      bf16x8 a  = *(const bf16x8*)(qs  + l31 * 1536 + (((kc + k8*16 + hi*8) * 2) ^ ((l31 & 7) << 4)));
      bf16x8 bv = *(const bf16x8*)(ksm + col * 256  + (((k8*16 + hi*8) * 2) ^ ((col & 7) << 4)));
      acc = __builtin_amdgcn_mfma_f32_32x32x16_bf16(a, bv, acc, 0, 0, 0);
    }
  }
  int ql = qlen[b], kl = klen[b];
  float kkv = kk[b * TT + col];
  float krv = kR[b * TT + col];
  bool cm = col < kl;
  #pragma unroll
  for (int r = 0; r < 16; ++r){
    int row = r0 + (r & 3) + 8 * (r >> 2) + 4 * hi;
    float qqv = qq[b * TT + row];
    float sq = qqv + kkv - 2.f * acc[r];
    float d = sqrtf(fmaxf(sq, 1e-12f));
    bool m = (row < ql) && cm;
    float dm = m ? d : 0.f;
    float pm = m ? fabsf(qR[b * TT + row] - krv) : 0.f;
    Dout[(((size_t)b * TT + row) << 7) + col] = dm;
    inb[(((size_t)b * TT + row) << 7) + col] = pack2bf(dm, pm);
  }
}

// ---------------- conv1: 2ch -> 30ch 5x5 via bf16 MFMA, fp8 out [b][y][x][c32] ----------------
#define C1_ROWW 136
__global__ __launch_bounds__(512, 2) void conv1_mfma_k(const u32* __restrict__ inb,
    const u16* __restrict__ w1c, const float* __restrict__ bias, u8* __restrict__ act1){
  __shared__ u32 ilds[12 * C1_ROWW];
  __shared__ __align__(16) char wlds[5120];
  __shared__ __align__(16) char tr[8 * 4096];
  int yg = blockIdx.x, bb = blockIdx.y;
  int y0 = yg * 8, tid = threadIdx.x;
  {
    const uint4* src = (const uint4*)w1c;
    uint4* dst = (uint4*)wlds;
    for (int i = tid; i < 320; i += 512) dst[i] = src[i];
  }
  for (int i = tid; i < 12 * C1_ROWW; i += 512){
    int r = i / C1_ROWW, xi = i - r * C1_ROWW;
    int gy = y0 - 2 + r, gx = xi - 2;
    u32 v = 0;
    if ((unsigned)gy < 128u && (unsigned)gx < 128u)
      v = inb[(((size_t)bb * 128 + gy) << 7) + gx];
    ilds[r * C1_ROWW + xi] = v;
  }
  __syncthreads();
  int lane = tid & 63, w = tid >> 6;
  int hi = lane >> 5, l31 = lane & 31;
  bf16x8 afr[5];
  #pragma unroll
  for (int dy = 0; dy < 5; ++dy)
    afr[dy] = *(const bf16x8*)(wlds + dy*1024 + (((l31<<5) + (hi<<4)) ^ ((l31&7)<<4)));
  float biasv[16];
  #pragma unroll
  for (int r = 0; r < 16; ++r){
    int oc = (r & 3) + 8*(r >> 2) + 4*hi;
    biasv[r] = (oc < MC) ? bias[oc] : 0.f;
  }
  int wbase = w * 4096;
  #pragma unroll
  for (int t = 0; t < 4; ++t){
    int px = t*32 + l31;
    f32x16 acc;
    #pragma unroll
    for (int r = 0; r < 16; ++r) acc[r] = 0.f;
    #pragma unroll
    for (int dy = 0; dy < 5; ++dy){
      const u32* rp = &ilds[(w + dy)*C1_ROWW + px + hi*4];
      union { u32 uw[4]; bf16x8 v; } ub;
      ub.uw[0] = rp[0]; ub.uw[1] = rp[1]; ub.uw[2] = rp[2]; ub.uw[3] = rp[3];
      acc = __builtin_amdgcn_mfma_f32_32x32x16_bf16(afr[dy], ub.v, acc, 0, 0, 0);
    }
    #pragma unroll
    for (int q = 0; q < 4; ++q){
      float v0 = fmaxf(acc[4*q+0] + biasv[4*q+0], 0.f);
      float v1 = fmaxf(acc[4*q+1] + biasv[4*q+1], 0.f);
      float v2 = fmaxf(acc[4*q+2] + biasv[4*q+2], 0.f);
      float v3 = fmaxf(acc[4*q+3] + biasv[4*q+3], 0.f);
      u32 word = pk_fp8<false>(v0, v1, 0u);
      word = pk_fp8<true>(v2, v3, word);
      int addr = wbase + (((px<<5) + (q<<3) + (hi<<2)) ^ ((px&7)<<3));
      *(u32*)(tr + addr) = word;
    }
  }
  int y = y0 + w;
  #pragma unroll
  for (int p = 0; p < 8; ++p){
    int x = p*16 + (lane >> 2), cg = lane & 3;
    int addr = wbase + (((x<<5) + (cg<<3)) ^ ((x&7)<<3));
    uint2 v = *(const uint2*)(tr + addr);
    *(uint2*)(act1 + ((((size_t)bb*128 + y)*128 + x) << 5) + cg*8) = v;
  }
}

// ---------------- conv2: 30->30 5x5 via fp8 MFMA, fully bank-swizzled LDS ----------------
#define C2_IN_ROWB 4224                 // 132 px * 32 B
#define C2_IN_BYTES (12*C2_IN_ROWB)     // 50688
#define C2_W_OFF C2_IN_BYTES
#define C2_SMEM (C2_W_OFF + 25*1024)    // 76288

__global__ __launch_bounds__(512, 4) void conv2_mfma_k(
    const u8* __restrict__ act1, const u8* __restrict__ w2p,
    const float* __restrict__ bias, u8* __restrict__ act2){
  __shared__ __align__(16) char smem[C2_SMEM];
  int yg = blockIdx.x;          // 0..15
  int bb = blockIdx.y;
  int y0 = yg * 8;
  int tid = threadIdx.x;
  // weights: linear copy (layout pre-swizzled in prep_w_k)
  {
    const uint4* src = (const uint4*)w2p;
    uint4* dst = (uint4*)(smem + C2_W_OFF);
    for (int i = tid; i < 1600; i += 512) dst[i] = src[i];
  }
  // stage input rows y0-2 .. y0+9 : [r][x132][ic32] fp8, XOR-swizzled
  for (int i = tid; i < 3168; i += 512){
    int r = i / 264; int t2 = i - r*264; int lx = t2 >> 1; int h = t2 & 1;
    int gy = y0 - 2 + r, gx = lx - 2;
    uint4 v = make_uint4(0,0,0,0);
    if ((unsigned)gy < 128u && (unsigned)gx < 128u)
      v = *(const uint4*)(act1 + ((((size_t)(bb*128 + gy)*128 + gx)) << 5) + (h << 4));
    int boff = ((lx << 5) + (h << 4)) ^ ((lx & 7) << 4);
    *(uint4*)(smem + r*C2_IN_ROWB + boff) = v;
  }
  __syncthreads();
  int lane = tid & 63, w = tid >> 6;
  int hi = lane >> 5, l31 = lane & 31;
  int aBase = C2_W_OFF + (((l31 << 5) + (hi << 4)) ^ ((l31 & 7) << 4));
  f32x16 acc[4];
  #pragma unroll
  for (int t = 0; t < 4; ++t)
    #pragma unroll
    for (int r = 0; r < 16; ++r) acc[t][r] = 0.f;
  #pragma unroll
  for (int dy = 0; dy < 5; ++dy){
    const char* rowp = smem + (w + dy)*C2_IN_ROWB;
    #pragma unroll
    for (int dx = 0; dx < 5; ++dx){
      ll2 a = *(const ll2*)(smem + aBase + (dy*5 + dx)*1024);
      #pragma unroll
      for (int t = 0; t < 4; ++t){
        int px2 = t*32 + l31 + dx;
        int boff = ((px2 << 5) + (hi << 4)) ^ ((px2 & 7) << 4);
        ll2 b = *(const ll2*)(rowp + boff);
        acc[t] = __builtin_amdgcn_mfma_f32_32x32x16_fp8_fp8(a.x, b.x, acc[t], 0, 0, 0);
        acc[t] = __builtin_amdgcn_mfma_f32_32x32x16_fp8_fp8(a.y, b.y, acc[t], 0, 0, 0);
      }
    }
  }
  float biasv[16];
  #pragma unroll
  for (int r = 0; r < 16; ++r){
    int oc = (r & 3) + 8*(r >> 2) + 4*hi;
    biasv[r] = (oc < MC) ? bias[oc] : 0.f;
  }
  __syncthreads();
  // transpose via LDS (per-wave 4KB region; 2-way-max swizzle)
  int wbase = w * 8192;
  #pragma unroll
  for (int t = 0; t < 4; ++t){
    int px = t*32 + l31;
    #pragma unroll
    for (int q = 0; q < 4; ++q){
      float v0 = fmaxf(acc[t][4*q+0] + biasv[4*q+0], 0.f);
      float v1 = fmaxf(acc[t][4*q+1] + biasv[4*q+1], 0.f);
      float v2 = fmaxf(acc[t][4*q+2] + biasv[4*q+2], 0.f);
      float v3 = fmaxf(acc[t][4*q+3] + biasv[4*q+3], 0.f);
      u32 word = pk_fp8<false>(v0, v1, 0u);
      word = pk_fp8<true>(v2, v3, word);
      int addr = wbase + (((px<<5) + (q<<3) + (hi<<2)) ^ (((px>>2)&3)<<3));
      *(u32*)(smem + addr) = word;
    }
  }
  int y = y0 + w;
  #pragma unroll
  for (int p = 0; p < 8; ++p){
    int x = p*16 + (lane >> 2), cg = lane & 3;
    int addr = wbase + (((x<<5) + (cg<<3)) ^ (((x>>2)&3)<<3));
    uint2 v = *(const uint2*)(smem + addr);
    *(uint2*)(act2 + ((((size_t)bb*128 + y)*128 + x) << 5) + cg*8) = v;
  }
}

// ---------------- conv3 + mask + row softmax + A write + row D*A ----------------
__global__ __launch_bounds__(512) void conv3sm_k(const u8* __restrict__ act2,
    const float* __restrict__ w3, const float* __restrict__ b3, const float* __restrict__ Dbuf,
    const int* __restrict__ qlen, const int* __restrict__ klen,
    float* __restrict__ Aout, float* __restrict__ rowsum, int b0){
  __shared__ float wlds[9][32];
  __shared__ float ex0[512], ex2[512];
  __shared__ float redm[8], reds[8], redd[8];
  int i  = blockIdx.x;
  int bb = blockIdx.y;
  int b  = b0 + bb;
  int tid = threadIdx.x;
  for (int idx = tid; idx < 288; idx += 512){
    int tap = idx >> 5, c = idx & 31;
    wlds[tap][c] = (c < MC) ? w3[c * 9 + tap] : 0.f;
  }
  __syncthreads();
  int px = tid >> 2, cg = tid & 3, wv = tid >> 6;
  float T0 = 0.f, T1 = 0.f, T2 = 0.f;
  #pragma unroll
  for (int dy = 0; dy < 3; ++dy){
    int gy = i - 1 + dy;
    uint2 v = make_uint2(0, 0);
    if ((unsigned)gy < 128u)
      v = *(const uint2*)(act2 + ((((size_t)bb*128 + gy)*128 + px) << 5) + cg*8);
    float x[8];
    upk_fp8x4(v.x, x);
    upk_fp8x4(v.y, x + 4);
    const float* w0p = &wlds[dy*3 + 0][cg*8];
    const float* w1p = &wlds[dy*3 + 1][cg*8];
    const float* w2q = &wlds[dy*3 + 2][cg*8];
    #pragma unroll
    for (int c = 0; c < 8; ++c){
      T0 = fmaf(x[c], w0p[c], T0);
      T1 = fmaf(x[c], w1p[c], T1);
      T2 = fmaf(x[c], w2q[c], T2);
    }
  }
  ex0[tid] = T0; ex2[tid] = T2;
  __syncthreads();
  float acc = T1;
  if (px > 0)   acc += ex0[tid - 4];
  if (px < 127) acc += ex2[tid + 4];
  acc += __shfl_xor(acc, 1);
  acc += __shfl_xor(acc, 2);
  acc += b3[0];
  float Dv = Dbuf[(((size_t)b * 128 + i) << 7) + px];
  bool m = (i < qlen[b]) && (px < klen[b]);
  float xv = m ? -(acc + Dv) : -100.f;
  float mx = xv;
  #pragma unroll
  for (int o = 32; o; o >>= 1) mx = fmaxf(mx, __shfl_xor(mx, o));
  if ((tid & 63) == 0) redm[wv] = mx;
  __syncthreads();
  mx = fmaxf(fmaxf(fmaxf(redm[0], redm[1]), fmaxf(redm[2], redm[3])),
             fmaxf(fmaxf(redm[4], redm[5]), fmaxf(redm[6], redm[7])));
  float e = __expf(xv - mx);
  float s  = e;
  float de = Dv * e;
  #pragma unroll
  for (int o = 32; o; o >>= 1){ s += __shfl_xor(s, o); de += __shfl_xor(de, o); }
  if ((tid & 63) == 0){ reds[wv] = s; redd[wv] = de; }
  __syncthreads();
  float s8  = (reds[0] + reds[1]) + (reds[2] + reds[3]) + (reds[4] + reds[5]) + (reds[6] + reds[7]);
  float a = e * 4.0f / s8;
  if (cg == 0) Aout[(((size_t)b * 128 + i) << 7) + px] = a;
  if (tid == 0){
    float d8 = (redd[0] + redd[1]) + (redd[2] + redd[3]) + (redd[4] + redd[5]) + (redd[6] + redd[7]);
    rowsum[b * TT + i] = d8 / s8;
  }
}

// ---------------- dis reduce ----------------
__global__ __launch_bounds__(128) void dis_k(const float* __restrict__ rowsum, float* __restrict__ out){
  int b = blockIdx.x, tid = threadIdx.x;
  float v = rowsum[b * TT + tid];
  #pragma unroll
  for (int o = 32; o; o >>= 1) v += __shfl_xor(v, o);
  __shared__ float red[2];
  if ((tid & 63) == 0) red[tid >> 6] = v;
  __syncthreads();
  if (tid == 0) out[b] = (red[0] + red[1]) * (1.0f / 128.0f);
}

extern "C" void kernel_launch(void* const* d_in, const int* in_sizes, int n_in,
                              void* d_out, int out_size, void* d_ws, size_t ws_size,
                              hipStream_t stream){
  const float* q_seq = (const float*)d_in[0];
  const int*   q_len = (const int*)d_in[1];
  const float* q_R   = (const float*)d_in[2];
  const float* k_seq = (const float*)d_in[3];
  const int*   k_len = (const int*)d_in[4];
  const float* k_R   = (const float*)d_in[5];
  const float* c1w   = (const float*)d_in[6];
  const float* c1b   = (const float*)d_in[7];
  const float* c2w   = (const float*)d_in[8];
  const float* c2b   = (const float*)d_in[9];
  const float* c3w   = (const float*)d_in[10];
  const float* c3b   = (const float*)d_in[11];
  float* out = (float*)d_out;

  char* base = (char*)d_ws;
  size_t off = 0;
  auto take = [&](size_t bytes)->char*{
    char* p = base + off;
    off = (off + bytes + 255) & ~(size_t)255;
    return p;
  };
  float* Dbuf   = (float*)take((size_t)NB * TT * TT * 4);
  float* qq     = (float*)take((size_t)NB * TT * 4);
  float* kkn    = (float*)take((size_t)NB * TT * 4);
  float* rowsum = (float*)take((size_t)NB * TT * 4);
  u32*   inb    = (u32*)  take((size_t)NB * TT * TT * 4);
  u8*    w2p    = (u8*)   take(25 * 1024);
  u16*   w1c    = (u16*)  take(5 * 1024);
  u16*   qb16   = (u16*)  take((size_t)NB * TT * DK * 2);
  u16*   kb16   = (u16*)  take((size_t)NB * TT * DK * 2);
  size_t fixed = off;
  int BCH = 64;
  while (BCH > 1 && fixed + (size_t)BCH * TT * TT * 64 + 1024 > ws_size) BCH >>= 1;
  u8* act1 = (u8*)take((size_t)BCH * TT * TT * 32);
  u8* act2 = (u8*)take((size_t)BCH * TT * TT * 32);

  prep_w_k<<<26, 256, 0, stream>>>(c2w, c1w, w2p, w1c);
  row_norms_k<<<4096, 256, 0, stream>>>(q_seq, k_seq, qq, kkn, qb16, kb16);
  cdist_mfma_k<<<dim3(4, NB), 256, 0, stream>>>(qb16, kb16, qq, kkn, q_len, k_len, q_R, k_R, Dbuf, inb);
  for (int b0 = 0; b0 < NB; b0 += BCH){
    int nb = BCH;
    conv1_mfma_k<<<dim3(16, nb), 512, 0, stream>>>(inb + (size_t)b0 * TT * TT, w1c, c1b, act1);
    conv2_mfma_k<<<dim3(16, nb), 512, 0, stream>>>(act1, w2p, c2b, act2);
    conv3sm_k<<<dim3(TT, nb), 512, 0, stream>>>(act2, c3w, c3b, Dbuf, q_len, k_len, out, rowsum, b0);
  }
  dis_k<<<NB, 128, 0, stream>>>(rowsum, out + (size_t)NB * TT * TT);
}